// Round 10
// baseline (98.558 us; speedup 1.0000x reference)
//
#include <hip/hip_runtime.h>

#define L_TOTAL   32768
#define E_DIM     64
#define K_TOTAL   1024
#define LTILES    2048                // L_TOTAL / 16
#define CTILES    64                  // K_TOTAL / 16
#define OUT_STRIDE 2097152            // L_TOTAL * E_DIM
#define XPAD      68

typedef _Float16 half_t;
typedef _Float16 half8  __attribute__((ext_vector_type(8)));
typedef float    floatx4 __attribute__((ext_vector_type(4)));

// ws layout (bytes)
#define WS_XH   0u                    // x hi frags [2048 lt][2 kt][64 lane][8] = 4 MB
#define WS_XL   4194304u              // x lo frags                              4 MB
#define WS_XX   8388608u              // ||x||^2 [32768]                       128 KB
#define WS_EH   8519680u              // e hi frags [64 ct][2 kt][64 lane][8]  128 KB
#define WS_EL   8650752u              // e lo frags                            128 KB
#define WS_EN   8781824u              // e norms C-layout [64 ct][64 lane][4]   64 KB
#define WS_PART 8847360u              // float2 [16 wset][32768 lat]             4 MB

// ---------------------------------------------------------------------------
// x fp32 -> f16 hi/lo in MFMA-B-fragment order + exact-order row norms.
// Block: 256 thr = 4 waves; wave handles one 16-row tile (staged via LDS).
// Norm: 16-elem fmaf chain per q-slice (kt0 then kt1), then xor16+xor32 —
// bit-identical to the R8 in-kernel reduction.
// ---------------------------------------------------------------------------
__global__ __launch_bounds__(256)
void vq_xconv_kernel(const float* __restrict__ x,
                     half_t* __restrict__ xh, half_t* __restrict__ xl,
                     float* __restrict__ xx) {
    __shared__ float s_x[64 * XPAD];
    const int tid  = threadIdx.x;
    const int wave = tid >> 6;
    const int lane = tid & 63;
    const int q    = lane >> 4;
    const int ln   = lane & 15;
    const int rbase = blockIdx.x * 64;

    const float4* xg = (const float4*)(x + (size_t)rbase * E_DIM);
    #pragma unroll
    for (int i = 0; i < 4; ++i) {
        const int f = i * 256 + tid;
        *(float4*)(&s_x[(f >> 4) * XPAD + (f & 15) * 4]) = xg[f];
    }
    __syncthreads();

    const int lt = blockIdx.x * 4 + wave;
    const float* xr = &s_x[(wave * 16 + ln) * XPAD + q * 8];
    half8 h[2], l[2];
    float sn = 0.f;
    #pragma unroll
    for (int kt = 0; kt < 2; ++kt) {
        float4 v0 = *(const float4*)(xr + kt * 32);
        float4 v1 = *(const float4*)(xr + kt * 32 + 4);
        float f[8] = {v0.x, v0.y, v0.z, v0.w, v1.x, v1.y, v1.z, v1.w};
        #pragma unroll
        for (int j = 0; j < 8; ++j) {
            half_t hh = (half_t)f[j];
            half_t ll = (half_t)(f[j] - (float)hh);
            h[kt][j] = hh;
            l[kt][j] = ll;
            sn = fmaf(f[j], f[j], sn);
        }
    }
    sn += __shfl_xor(sn, 16, 64);
    sn += __shfl_xor(sn, 32, 64);
    #pragma unroll
    for (int kt = 0; kt < 2; ++kt) {
        *(half8*)(xh + ((size_t)(lt * 2 + kt) * 64 + lane) * 8) = h[kt];
        *(half8*)(xl + ((size_t)(lt * 2 + kt) * 64 + lane) * 8) = l[kt];
    }
    if (lane < 16) xx[lt * 16 + ln] = sn;
}

// ---------------------------------------------------------------------------
// Codebook fp32 -> f16 hi/lo A-fragments + norms in C-layout (exact R8 tree).
// Fragment (ct,kt,lane) = e[ct*16 + (lane&15)][kt*32 + (lane>>4)*8 .. +8].
// ---------------------------------------------------------------------------
__global__ __launch_bounds__(128)
void vq_eswz_kernel(const float* __restrict__ emb,
                    half_t* __restrict__ eh, half_t* __restrict__ el,
                    float* __restrict__ enc) {
    __shared__ float s_p[128];
    __shared__ float s_n[16];
    const int ct   = blockIdx.x;
    const int t    = threadIdx.x;
    const int kt   = t >> 6;
    const int lane = t & 63;
    const int q    = lane >> 4;
    const int ln   = lane & 15;

    const float* src = emb + (size_t)(ct * 16 + ln) * E_DIM + kt * 32 + q * 8;
    float4 v0 = *(const float4*)src;
    float4 v1 = *(const float4*)(src + 4);
    float f[8] = {v0.x, v0.y, v0.z, v0.w, v1.x, v1.y, v1.z, v1.w};

    half8 h, l;
    float s = 0.f;
    #pragma unroll
    for (int j = 0; j < 8; ++j) {
        half_t hh = (half_t)f[j];
        half_t ll = (half_t)(f[j] - (float)hh);
        h[j] = hh;
        l[j] = ll;
        s = fmaf(f[j], f[j], s);
    }
    *(half8*)(eh + ((size_t)(ct * 2 + kt) * 64 + lane) * 8) = h;
    *(half8*)(el + ((size_t)(ct * 2 + kt) * 64 + lane) * 8) = l;

    s_p[t] = s;
    __syncthreads();
    if (t < 16) {
        float n = 0.f;
        #pragma unroll
        for (int u = 0; u < 8; ++u)
            n += s_p[(u >> 2) * 64 + (u & 3) * 16 + t];
        s_n[t] = n;
    }
    __syncthreads();
    if (t < 64) {
        const int qq = t >> 4;
        floatx4 e4 = {s_n[qq * 4], s_n[qq * 4 + 1], s_n[qq * 4 + 2], s_n[qq * 4 + 3]};
        *(floatx4*)(enc + ct * 256 + t * 4) = e4;
    }
}

// ---------------------------------------------------------------------------
// Inverted-GEMM distances + per-step argmin. A = 64 resident codebook codes
// (wset = quarter*4 + wave), B = streamed x fragments. Grid 1024 =
// 4 quarters x 256 latent-groups; 8 latent-tiles per block. NO LDS, NO
// barriers, 2-register argmin state, 1-deep B prefetch. Partials
// (best,idx) per (wset, latent) -> ws. Distances bit-identical to R8.
// ---------------------------------------------------------------------------
__global__ __launch_bounds__(256, 3)
void vq_dist_kernel(const half_t* __restrict__ xh, const half_t* __restrict__ xl,
                    const float* __restrict__ xx,
                    const half_t* __restrict__ eh, const half_t* __restrict__ el,
                    const float* __restrict__ enc,
                    float2* __restrict__ partial) {
    const int tid   = threadIdx.x;
    const int wave  = tid >> 6;
    const int lane  = tid & 63;
    const int q     = lane >> 4;
    const int ln    = lane & 15;
    const int quarter = blockIdx.x & 3;
    const int lgroup  = blockIdx.x >> 2;    // 0..255
    const int wset  = quarter * 4 + wave;   // 0..15, codes wset*64..+64
    const int lt0   = lgroup * 8;           // 8 latent tiles per block

    // ---- resident A: 64 codes hi/lo + their norms (C-layout)
    half8 Ah[4][2], Al[4][2];
    floatx4 en4[4];
    #pragma unroll
    for (int rt = 0; rt < 4; ++rt) {
        const int ct = wset * 4 + rt;
        #pragma unroll
        for (int kt = 0; kt < 2; ++kt) {
            Ah[rt][kt] = *(const half8*)(eh + ((size_t)(ct * 2 + kt) * 64 + lane) * 8);
            Al[rt][kt] = *(const half8*)(el + ((size_t)(ct * 2 + kt) * 64 + lane) * 8);
        }
        en4[rt] = *(const floatx4*)(enc + ct * 256 + lane * 4);
    }

    half8 p0, p1, p2, p3; float pxx;   // prefetch buffer
    half8 c0, c1, c2, c3; float cxx;   // current buffer
#define LOADX(J) { const size_t lt_ = (size_t)(lt0 + (J));                     \
        p0 = *(const half8*)(xh + ((lt_ * 2 + 0) * 64 + lane) * 8);            \
        p1 = *(const half8*)(xh + ((lt_ * 2 + 1) * 64 + lane) * 8);            \
        p2 = *(const half8*)(xl + ((lt_ * 2 + 0) * 64 + lane) * 8);            \
        p3 = *(const half8*)(xl + ((lt_ * 2 + 1) * 64 + lane) * 8);            \
        pxx = xx[lt_ * 16 + ln]; }

    LOADX(0)
    #pragma unroll 1
    for (int j = 0; j < 8; ++j) {
        c0 = p0; c1 = p1; c2 = p2; c3 = p3; cxx = pxx;
        if (j < 7) LOADX(j + 1)

        float best = 3.402823466e+38f;
        int   bidx = 0;
        #pragma unroll
        for (int rt = 0; rt < 4; ++rt) {
            floatx4 Ca = {0.f, 0.f, 0.f, 0.f};
            floatx4 Cb = {0.f, 0.f, 0.f, 0.f};
            // Ca: eh.xh (kt0,kt1) == R8's xh.eh order
            Ca = __builtin_amdgcn_mfma_f32_16x16x32_f16(Ah[rt][0], c0, Ca, 0, 0, 0);
            Ca = __builtin_amdgcn_mfma_f32_16x16x32_f16(Ah[rt][1], c1, Ca, 0, 0, 0);
            // Cb sequence mirrors R8: xl.eh(kt0), xl.eh(kt1), xh.el(kt0), xh.el(kt1)
            Cb = __builtin_amdgcn_mfma_f32_16x16x32_f16(Ah[rt][0], c2, Cb, 0, 0, 0);
            Cb = __builtin_amdgcn_mfma_f32_16x16x32_f16(Ah[rt][1], c3, Cb, 0, 0, 0);
            Cb = __builtin_amdgcn_mfma_f32_16x16x32_f16(Al[rt][0], c0, Cb, 0, 0, 0);
            Cb = __builtin_amdgcn_mfma_f32_16x16x32_f16(Al[rt][1], c1, Cb, 0, 0, 0);
            #pragma unroll
            for (int r = 0; r < 4; ++r) {
                float dot = Ca[r] + Cb[r];
                float d = __fadd_rn(__fsub_rn(cxx, __fmul_rn(2.0f, dot)), en4[rt][r]);
                const int kg = (wset * 4 + rt) * 16 + q * 4 + r;
                if (d < best) { best = d; bidx = kg; }  // in-lane codes ascending
            }
        }
        // cross-quad lexicographic merge (ties -> lower code index)
        #pragma unroll
        for (int o = 16; o <= 32; o <<= 1) {
            float ob = __shfl_xor(best, o, 64);
            int   oi = __shfl_xor(bidx, o, 64);
            if (ob < best || (ob == best && oi < bidx)) { best = ob; bidx = oi; }
        }
        if (lane < 16)
            partial[(size_t)wset * L_TOTAL + (size_t)(lt0 + j) * 16 + ln] =
                make_float2(best, __int_as_float(bidx));
    }
#undef LOADX
}

// ---------------------------------------------------------------------------
// Merge 16 wset-partials per latent (lexicographic == first occurrence),
// then coalesced epilogue: out0 = x, out1 = emb[idx], out2 = (x+q)-x.
// Grid 512 x 256 (64 latents / block).
// ---------------------------------------------------------------------------
__global__ __launch_bounds__(256)
void vq_epilogue_kernel(const float* __restrict__ x,
                        const float* __restrict__ emb,
                        const float2* __restrict__ partial,
                        float* __restrict__ out) {
    __shared__ int s_fin[64];
    const int tid  = threadIdx.x;
    const int base = blockIdx.x * 64;

    if (tid < 64) {
        float b = 3.402823466e+38f;
        int   i = 0x7fffffff;
        #pragma unroll
        for (int s = 0; s < 16; ++s) {
            float2 p = partial[(size_t)s * L_TOTAL + base + tid];
            int    pi = __float_as_int(p.y);
            if (p.x < b || (p.x == b && pi < i)) { b = p.x; i = pi; }
        }
        s_fin[tid] = i;
        out[3 * (size_t)OUT_STRIDE + base + tid] = (float)i;   // coalesced
    }
    __syncthreads();

    const size_t fb = (size_t)base * (E_DIM / 4);
    const float4* xg = (const float4*)x + fb;
    float4* o0 = (float4*)out + fb;
    float4* o1 = (float4*)(out + OUT_STRIDE) + fb;
    float4* o2 = (float4*)(out + 2 * (size_t)OUT_STRIDE) + fb;
    #pragma unroll
    for (int i = 0; i < 4; ++i) {
        const int f   = i * 256 + tid;
        const int row = f >> 4;
        const int col = (f & 15) * 4;
        const float4 xv = xg[f];
        const int idx = s_fin[row];
        const float4 qv = *(const float4*)(emb + (size_t)idx * E_DIM + col);
        float4 z;
        z.x = __fsub_rn(__fadd_rn(xv.x, qv.x), xv.x);
        z.y = __fsub_rn(__fadd_rn(xv.y, qv.y), xv.y);
        z.z = __fsub_rn(__fadd_rn(xv.z, qv.z), xv.z);
        z.w = __fsub_rn(__fadd_rn(xv.w, qv.w), xv.w);
        o0[f] = xv;
        o1[f] = qv;
        o2[f] = z;
    }
}

// ---------------------------------------------------------------------------
extern "C" void kernel_launch(void* const* d_in, const int* in_sizes, int n_in,
                              void* d_out, int out_size, void* d_ws, size_t ws_size,
                              hipStream_t stream) {
    const float* x   = (const float*)d_in[0];
    const float* emb = (const float*)d_in[1];
    float* out = (float*)d_out;

    char* ws = (char*)d_ws;
    half_t* xhp = (half_t*)(ws + WS_XH);
    half_t* xlp = (half_t*)(ws + WS_XL);
    float*  xxp = (float*)(ws + WS_XX);
    half_t* ehp = (half_t*)(ws + WS_EH);
    half_t* elp = (half_t*)(ws + WS_EL);
    float*  enp = (float*)(ws + WS_EN);
    float2* prt = (float2*)(ws + WS_PART);

    hipLaunchKernelGGL(vq_xconv_kernel, dim3(LTILES / 4), dim3(256), 0, stream,
                       x, xhp, xlp, xxp);
    hipLaunchKernelGGL(vq_eswz_kernel, dim3(CTILES), dim3(128), 0, stream,
                       emb, ehp, elp, enp);
    hipLaunchKernelGGL(vq_dist_kernel, dim3(1024), dim3(256), 0, stream,
                       xhp, xlp, xxp, ehp, elp, enp, prt);
    hipLaunchKernelGGL(vq_epilogue_kernel, dim3(512), dim3(256), 0, stream,
                       x, emb, prt, out);
}